// Round 1
// baseline (455.937 us; speedup 1.0000x reference)
//
#include <hip/hip_runtime.h>

#define B_N 4096
#define T_N 64
#define K_N 512
#define D_N 64

// ws layout:
//   [0, 131072)        : c2[t*K+k]  (32768 floats)  -- |c|^2 per code
//   [131072, 262144)   : used[t*K+k] (32768 uints)
//   [262144, 262152)   : loss_sum (double)

__global__ __launch_bounds__(256) void zero_ws_kernel(unsigned* __restrict__ used,
                                                      double* __restrict__ loss) {
    int i = blockIdx.x * 256 + threadIdx.x;
    if (i < T_N * K_N) used[i] = 0u;
    if (i == 0) *loss = 0.0;
}

// |c|^2 per (t,k): sequential sum of pre-rounded squares (no FMA contraction),
// matching jnp.sum(codebooks*codebooks, axis=-1): products rounded, then summed.
__global__ __launch_bounds__(256) void c2_kernel(const float* __restrict__ cb,
                                                 float* __restrict__ c2) {
    int i = blockIdx.x * 256 + threadIdx.x;  // t*K + k
    if (i >= T_N * K_N) return;
    const float* c = cb + (size_t)i * D_N;
    float s = 0.0f;
#pragma unroll
    for (int d = 0; d < D_N; ++d) s = __fadd_rn(s, __fmul_rn(c[d], c[d]));
    c2[i] = s;
}

// Main: one thread per (b,t) row. Distances replicated as
//   fl( fl(A - 2*dot) + c2 )   with dot = ascending-d FMA chain.
__global__ __launch_bounds__(256) void vq_main(const float* __restrict__ z_e,
                                               const float* __restrict__ cb,
                                               const float* __restrict__ c2,
                                               float* __restrict__ zq_out,
                                               float* __restrict__ tok_out,
                                               unsigned* __restrict__ used,
                                               double* __restrict__ loss_sum) {
    const int t = blockIdx.y;
    const int b = blockIdx.x * 256 + threadIdx.x;

    const float* zrow = z_e + ((size_t)b * T_N + t) * D_N;
    float z[D_N];
#pragma unroll
    for (int d4 = 0; d4 < D_N / 4; ++d4) {
        float4 v = reinterpret_cast<const float4*>(zrow)[d4];
        z[4 * d4 + 0] = v.x; z[4 * d4 + 1] = v.y;
        z[4 * d4 + 2] = v.z; z[4 * d4 + 3] = v.w;
    }

    // A = sum(z*z): pre-rounded products, sequential adds (no contraction).
    float A = 0.0f;
#pragma unroll
    for (int d = 0; d < D_N; ++d) A = __fadd_rn(A, __fmul_rn(z[d], z[d]));

    const float* cbt = cb + (size_t)t * K_N * D_N;
    const float* c2t = c2 + t * K_N;

    float best = __builtin_inff();
    int tok = 0;
    for (int k = 0; k < K_N; ++k) {
        const float* ck = cbt + (size_t)k * D_N;
        float acc = 0.0f;
#pragma unroll
        for (int d = 0; d < D_N; ++d) acc = __builtin_fmaf(z[d], ck[d], acc);
        // dist = fl( fl(A - fl(2*acc)) + c2 ); 2*acc is exact.
        float dist = __fadd_rn(__fsub_rn(A, __fmul_rn(2.0f, acc)), c2t[k]);
        if (dist < best) { best = dist; tok = k; }   // strict < : first-occurrence ties
    }

    // Outputs: z_q_st == z_q (codebook row), tokens as float, loss contribution.
    const float* q = cbt + (size_t)tok * D_N;
    float* zq = zq_out + ((size_t)b * T_N + t) * D_N;
    double ld = 0.0;
#pragma unroll
    for (int d4 = 0; d4 < D_N / 4; ++d4) {
        float4 qv = reinterpret_cast<const float4*>(q)[d4];
        reinterpret_cast<float4*>(zq)[d4] = qv;
        float d0 = z[4 * d4 + 0] - qv.x;
        float d1 = z[4 * d4 + 1] - qv.y;
        float d2 = z[4 * d4 + 2] - qv.z;
        float d3 = z[4 * d4 + 3] - qv.w;
        ld += (double)d0 * d0 + (double)d1 * d1 + (double)d2 * d2 + (double)d3 * d3;
    }
    tok_out[(size_t)b * T_N + t] = (float)tok;
    used[t * K_N + tok] = 1u;

    __shared__ double sred[256];
    sred[threadIdx.x] = ld;
    __syncthreads();
    for (int s = 128; s > 0; s >>= 1) {
        if (threadIdx.x < s) sred[threadIdx.x] += sred[threadIdx.x + s];
        __syncthreads();
    }
    if (threadIdx.x == 0) atomicAdd(loss_sum, sred[0]);
}

__global__ __launch_bounds__(512) void finalize_kernel(const unsigned* __restrict__ used,
                                                       const double* __restrict__ loss_sum,
                                                       float* __restrict__ out) {
    __shared__ unsigned s[512];
    unsigned c = 0;
    for (int i = threadIdx.x; i < T_N * K_N; i += 512) c += used[i];
    s[threadIdx.x] = c;
    __syncthreads();
    for (int st = 256; st > 0; st >>= 1) {
        if (threadIdx.x < st) s[threadIdx.x] += s[threadIdx.x + st];
        __syncthreads();
    }
    if (threadIdx.x == 0) {
        const size_t base = (size_t)B_N * T_N * D_N + (size_t)B_N * T_N;
        out[base]     = (float)(0.25 * (*loss_sum) / (double)((size_t)B_N * T_N * D_N));
        out[base + 1] = (float)s[0] / (float)(T_N * K_N);
    }
}

extern "C" void kernel_launch(void* const* d_in, const int* in_sizes, int n_in,
                              void* d_out, int out_size, void* d_ws, size_t ws_size,
                              hipStream_t stream) {
    const float* z_e = (const float*)d_in[0];
    const float* cb  = (const float*)d_in[1];
    float* out = (float*)d_out;

    float*    c2   = (float*)d_ws;
    unsigned* used = (unsigned*)((char*)d_ws + 131072);
    double*   loss = (double*)((char*)d_ws + 262144);

    zero_ws_kernel<<<128, 256, 0, stream>>>(used, loss);
    c2_kernel<<<128, 256, 0, stream>>>(cb, c2);

    float* tok_out = out + (size_t)B_N * T_N * D_N;
    vq_main<<<dim3(B_N / 256, T_N), 256, 0, stream>>>(z_e, cb, c2, out, tok_out, used, loss);

    finalize_kernel<<<1, 512, 0, stream>>>(used, loss, out);
}

// Round 2
// 399.640 us; speedup vs baseline: 1.1409x; 1.1409x over previous
//
#include <hip/hip_runtime.h>

#define B_N 4096
#define T_N 64
#define K_N 512
#define D_N 64
#define KC 64              // codes per LDS chunk
#define NCHUNK (K_N / KC)  // 8

// ws layout:
//   [0, 131072)        : c2[t*K+k]  (32768 floats)
//   [131072, 262144)   : used[t*K+k] (32768 uints)
//   [262144, 262152)   : loss_sum (double)

// prep: zero used/loss + |c|^2 per code (pre-rounded squares, sequential adds).
__global__ __launch_bounds__(256) void prep_kernel(const float* __restrict__ cb,
                                                   float* __restrict__ c2,
                                                   unsigned* __restrict__ used,
                                                   double* __restrict__ loss) {
    int i = blockIdx.x * 256 + threadIdx.x;   // < 32768
    used[i] = 0u;
    if (i == 0) *loss = 0.0;
    const float4* c = reinterpret_cast<const float4*>(cb + (size_t)i * D_N);
    float s = 0.0f;
#pragma unroll
    for (int j = 0; j < 16; ++j) {
        float4 v = c[j];
        s = __fadd_rn(s, __fmul_rn(v.x, v.x));
        s = __fadd_rn(s, __fmul_rn(v.y, v.y));
        s = __fadd_rn(s, __fmul_rn(v.z, v.z));
        s = __fadd_rn(s, __fmul_rn(v.w, v.w));
    }
    c2[i] = s;
}

// Main: block = 256 threads, fixed t, 512 consecutive b-rows (M=2 rows/thread,
// both z rows pinned in VGPRs). Codebook streamed through LDS in 64-code
// chunks (block-uniform reads -> broadcast, no conflicts), double-buffered
// with register-staged prefetch. Distances replicated exactly as
// fl( fl(A - 2*dot) + c2 ), dot = ascending-d FMA chain, strict-< argmin.
__global__ __launch_bounds__(256, 2) void vq_main(const float* __restrict__ z_e,
                                                  const float* __restrict__ cb,
                                                  const float* __restrict__ c2,
                                                  float* __restrict__ zq_out,
                                                  float* __restrict__ tok_out,
                                                  unsigned* __restrict__ used,
                                                  double* __restrict__ loss_sum) {
    const int t   = blockIdx.y;
    const int tid = threadIdx.x;
    const int b0  = blockIdx.x * 512 + 2 * tid;
    const int b1  = b0 + 1;

    __shared__ __align__(16) float cbuf[2][KC * D_N];  // 2 x 16 KB
    __shared__ __align__(16) float c2buf[2][KC];

    // z rows -> registers (16 float4 each, contiguous 256B per row)
    float z0[D_N], z1[D_N];
    const float* zr0 = z_e + ((size_t)b0 * T_N + t) * D_N;
    const float* zr1 = z_e + ((size_t)b1 * T_N + t) * D_N;
#pragma unroll
    for (int j = 0; j < 16; ++j) {
        float4 v0 = reinterpret_cast<const float4*>(zr0)[j];
        float4 v1 = reinterpret_cast<const float4*>(zr1)[j];
        z0[4*j+0] = v0.x; z0[4*j+1] = v0.y; z0[4*j+2] = v0.z; z0[4*j+3] = v0.w;
        z1[4*j+0] = v1.x; z1[4*j+1] = v1.y; z1[4*j+2] = v1.z; z1[4*j+3] = v1.w;
    }

    // A = sum(z*z): pre-rounded products, sequential adds (matches jnp).
    float A0 = 0.0f, A1 = 0.0f;
#pragma unroll
    for (int d = 0; d < D_N; ++d) A0 = __fadd_rn(A0, __fmul_rn(z0[d], z0[d]));
#pragma unroll
    for (int d = 0; d < D_N; ++d) A1 = __fadd_rn(A1, __fmul_rn(z1[d], z1[d]));

    const float* cbt = cb + (size_t)t * K_N * D_N;
    const float* c2t = c2 + t * K_N;

    // chunk staging registers
    float4 pf[4];
    float4 c2pf;

    auto issue = [&](int c) {
        const float4* src = reinterpret_cast<const float4*>(cbt + (size_t)c * KC * D_N);
#pragma unroll
        for (int j = 0; j < 4; ++j) pf[j] = src[j * 256 + tid];
        if (tid < 16) c2pf = reinterpret_cast<const float4*>(c2t + c * KC)[tid];
    };
    auto writebuf = [&](int buf) {
#pragma unroll
        for (int j = 0; j < 4; ++j) reinterpret_cast<float4*>(cbuf[buf])[j * 256 + tid] = pf[j];
        if (tid < 16) reinterpret_cast<float4*>(c2buf[buf])[tid] = c2pf;
    };

    issue(0);
    writebuf(0);
    __syncthreads();

    float best0 = __builtin_inff(), best1 = __builtin_inff();
    int tok0 = 0, tok1 = 0;

    for (int c = 0; c < NCHUNK; ++c) {
        if (c < NCHUNK - 1) issue(c + 1);   // global loads in flight over compute
        const float* cc  = cbuf[c & 1];
        const float* c2c = c2buf[c & 1];
        for (int kk = 0; kk < KC; ++kk) {
            const float* crow = cc + kk * D_N;
            float a0 = 0.0f, a1 = 0.0f;
#pragma unroll
            for (int d = 0; d < D_N; ++d) {
                float cd = crow[d];
                a0 = __builtin_fmaf(z0[d], cd, a0);
                a1 = __builtin_fmaf(z1[d], cd, a1);
            }
            float c2k = c2c[kk];
            float dist0 = __fadd_rn(__fsub_rn(A0, __fmul_rn(2.0f, a0)), c2k);
            float dist1 = __fadd_rn(__fsub_rn(A1, __fmul_rn(2.0f, a1)), c2k);
            int k = c * KC + kk;
            if (dist0 < best0) { best0 = dist0; tok0 = k; }
            if (dist1 < best1) { best1 = dist1; tok1 = k; }
        }
        if (c < NCHUNK - 1) {
            __syncthreads();               // everyone done reading cbuf[c&1]
            writebuf((c + 1) & 1);
            __syncthreads();               // next chunk visible
        }
    }

    // Epilogue: z_q_st = codebook row of winner; loss in double.
    const float* q0 = cbt + (size_t)tok0 * D_N;
    const float* q1 = cbt + (size_t)tok1 * D_N;
    float* zq0 = zq_out + ((size_t)b0 * T_N + t) * D_N;
    float* zq1 = zq_out + ((size_t)b1 * T_N + t) * D_N;
    double ld = 0.0;
#pragma unroll
    for (int j = 0; j < 16; ++j) {
        float4 qv = reinterpret_cast<const float4*>(q0)[j];
        reinterpret_cast<float4*>(zq0)[j] = qv;
        float d0 = z0[4*j+0] - qv.x, d1 = z0[4*j+1] - qv.y;
        float d2 = z0[4*j+2] - qv.z, d3 = z0[4*j+3] - qv.w;
        ld += (double)d0*d0 + (double)d1*d1 + (double)d2*d2 + (double)d3*d3;
    }
#pragma unroll
    for (int j = 0; j < 16; ++j) {
        float4 qv = reinterpret_cast<const float4*>(q1)[j];
        reinterpret_cast<float4*>(zq1)[j] = qv;
        float d0 = z1[4*j+0] - qv.x, d1 = z1[4*j+1] - qv.y;
        float d2 = z1[4*j+2] - qv.z, d3 = z1[4*j+3] - qv.w;
        ld += (double)d0*d0 + (double)d1*d1 + (double)d2*d2 + (double)d3*d3;
    }
    tok_out[(size_t)b0 * T_N + t] = (float)tok0;
    tok_out[(size_t)b1 * T_N + t] = (float)tok1;
    used[t * K_N + tok0] = 1u;
    used[t * K_N + tok1] = 1u;

    // block-reduce loss (reuse cbuf as double scratch after barrier)
    __syncthreads();
    double* red = reinterpret_cast<double*>(cbuf[0]);
    red[tid] = ld;
    __syncthreads();
    for (int s = 128; s > 0; s >>= 1) {
        if (tid < s) red[tid] += red[tid + s];
        __syncthreads();
    }
    if (tid == 0) atomicAdd(loss_sum, red[0]);
}

__global__ __launch_bounds__(1024) void finalize_kernel(const unsigned* __restrict__ used,
                                                        const double* __restrict__ loss_sum,
                                                        float* __restrict__ out) {
    __shared__ unsigned s[1024];
    const uint4* u4 = reinterpret_cast<const uint4*>(used);
    unsigned c = 0;
#pragma unroll
    for (int i = 0; i < 8; ++i) {
        uint4 v = u4[threadIdx.x + i * 1024];
        c += v.x + v.y + v.z + v.w;
    }
    s[threadIdx.x] = c;
    __syncthreads();
    for (int st = 512; st > 0; st >>= 1) {
        if (threadIdx.x < st) s[threadIdx.x] += s[threadIdx.x + st];
        __syncthreads();
    }
    if (threadIdx.x == 0) {
        const size_t base = (size_t)B_N * T_N * D_N + (size_t)B_N * T_N;
        out[base]     = (float)(0.25 * (*loss_sum) / (double)((size_t)B_N * T_N * D_N));
        out[base + 1] = (float)s[0] / (float)(T_N * K_N);
    }
}

extern "C" void kernel_launch(void* const* d_in, const int* in_sizes, int n_in,
                              void* d_out, int out_size, void* d_ws, size_t ws_size,
                              hipStream_t stream) {
    const float* z_e = (const float*)d_in[0];
    const float* cb  = (const float*)d_in[1];
    float* out = (float*)d_out;

    float*    c2   = (float*)d_ws;
    unsigned* used = (unsigned*)((char*)d_ws + 131072);
    double*   loss = (double*)((char*)d_ws + 262144);

    prep_kernel<<<128, 256, 0, stream>>>(cb, c2, used, loss);

    float* tok_out = out + (size_t)B_N * T_N * D_N;
    vq_main<<<dim3(B_N / 512, T_N), 256, 0, stream>>>(z_e, cb, c2, out, tok_out, used, loss);

    finalize_kernel<<<1, 1024, 0, stream>>>(used, loss, out);
}